// Round 5
// baseline (120.577 us; speedup 1.0000x reference)
//
#include <hip/hip_runtime.h>

#define BATCH 32
#define NROWS 8192
#define IND   128
#define HC    128
#define NEG   0.2f
#define NBLK  32                          // blocks per batch
#define ROWS  64                          // rows per iteration per block
#define ITERS (NROWS / (NBLK * ROWS))     // 4
#define PART_STRIDE 136                   // 4 M + 4 S + 128 P floats

typedef __attribute__((ext_vector_type(8))) short short8;
typedef __attribute__((ext_vector_type(4))) float f32x4;

// lgkm-only barrier: orders LDS, leaves global ops (gll DMA, out-stores) in flight
#define BARRIER()  asm volatile("s_waitcnt lgkmcnt(0)\n\ts_barrier" ::: "memory")
#define WAIT_VM0() asm volatile("s_waitcnt vmcnt(0)" ::: "memory")

__device__ __forceinline__ unsigned short f2bf(float f) {
    unsigned u = __float_as_uint(f);
    u += 0x7FFFu + ((u >> 16) & 1u);      // round-to-nearest-even
    return (unsigned short)(u >> 16);
}
__device__ __forceinline__ unsigned pack2(float a, float b) {
    return (unsigned)f2bf(a) | ((unsigned)f2bf(b) << 16);
}

// ---------------- kernel A: x_l for center rows only (B rows) ----------------
__global__ void gat_center(const float* __restrict__ x, const float* __restrict__ Wl,
                           const float* __restrict__ bl, float* __restrict__ xl0)
{
    const int b = blockIdx.x, t = threadIdx.x;   // 128 threads
    __shared__ float xrow[128];
    xrow[t] = x[(size_t)b * NROWS * IND + t];
    __syncthreads();
    float acc = bl[t];
#pragma unroll 16
    for (int k = 0; k < 128; ++k) acc = fmaf(xrow[k], Wl[k * 128 + t], acc);
    xl0[b * 128 + t] = acc;
}

// ---------------- kernel B: x_r GEMM + logits + online-softmax partials ------
// x staged via global_load_lds (f32, 16B-unit XOR swizzle through pre-swizzled
// SOURCE addresses); W_r fragments loaded straight from global into regs.
// Entire epilogue (bias, out-store, logits, online softmax, P-partial) is
// register/shuffle-only: wave wv owns head wv (cols wv*32..wv*32+31).
// 2 barriers per iteration; next tile's DMA overlaps the epilogue.
__global__ __launch_bounds__(256, 4) void gat_main(
    const float* __restrict__ x, const float* __restrict__ Wr,
    const float* __restrict__ br, const float* __restrict__ att,
    const float* __restrict__ xl0, float* __restrict__ out,
    float* __restrict__ part)
{
    const int tid  = threadIdx.x;
    const int lane = tid & 63;
    const int wv   = tid >> 6;
    const int b    = blockIdx.x >> 5;          // NBLK = 32
    const int blk  = blockIdx.x & (NBLK - 1);

    __shared__ float xt[ROWS * IND];           // 32 KB f32 x-tile, unit-swizzled

    // gll mapping: LDS 16B-unit D = i*256+tid holds x[r][4*((D&31)^(r&7))..+3],
    // r = D>>5.  LDS dest is linear (base + lane*16), source is per-lane swizzled.
    int goff[8];
#pragma unroll
    for (int i = 0; i < 8; ++i) {
        int D = i * 256 + tid, r = D >> 5, u = (D & 31) ^ (r & 7);
        goff[i] = r * IND + u * 4;
    }
    const size_t xorg = ((size_t)b * NROWS + blk * (ITERS * ROWS)) * IND;

    // ---- issue tile-0 DMA immediately (overlaps W_r fragment loads below)
    {
        const float* src = x + xorg;
#pragma unroll
        for (int i = 0; i < 8; ++i)
            __builtin_amdgcn_global_load_lds(
                (const __attribute__((address_space(1))) unsigned*)(src + goff[i]),
                (__attribute__((address_space(3))) unsigned*)(xt + (i * 256 + tid) * 4),
                16, 0, 0);
    }

    // ---- W_r fragments straight from global (64 KB/block, L2-hot after 1st)
    short8 bfr[2][4];
    {
        const int ksel = lane >> 4;
#pragma unroll
        for (int ct = 0; ct < 2; ++ct) {
            const int n = wv * 32 + ct * 16 + (lane & 15);
#pragma unroll
            for (int ks = 0; ks < 4; ++ks) {
                const int k0 = ks * 32 + ksel * 8;
                const float* wp = Wr + (size_t)k0 * HC + n;
                float v0 = wp[0 * HC], v1 = wp[1 * HC], v2 = wp[2 * HC], v3 = wp[3 * HC];
                float v4 = wp[4 * HC], v5 = wp[5 * HC], v6 = wp[6 * HC], v7 = wp[7 * HC];
                union { short8 s; unsigned u[4]; } t;
                t.u[0] = pack2(v0, v1); t.u[1] = pack2(v2, v3);
                t.u[2] = pack2(v4, v5); t.u[3] = pack2(v6, v7);
                bfr[ct][ks] = t.s;
            }
        }
    }

    // ---- per-lane head-local parameters (head = wv)
    const int   c0 = wv * 32 + (lane & 15), c1 = c0 + 16;
    const float q0 = xl0[b * 128 + c0], q1 = xl0[b * 128 + c1];
    const float a0 = att[c0],           a1 = att[c1];
    const float bi0 = br[c0],           bi1 = br[c1];

    float Mrun = -INFINITY, Srun = 0.f, P0 = 0.f, P1 = 0.f;

    for (int it = 0; it < ITERS; ++it) {
        WAIT_VM0();            // this wave's tile DMA (and prior stores) done
        BARRIER();             // all waves' DMA landed

        // ---- MFMA: 64 rows x this wave's 32 cols, K=128 (cvt f32->bf16 at read)
        f32x4 acc[4][2];
#pragma unroll
        for (int i = 0; i < 4; ++i)
#pragma unroll
            for (int j = 0; j < 2; ++j) acc[i][j] = (f32x4){0.f, 0.f, 0.f, 0.f};
        {
            const int ksel = lane >> 4;
#pragma unroll
            for (int rt = 0; rt < 4; ++rt) {
                const int rA = rt * 16 + (lane & 15);
                const int sw = rA & 7;
                short8 afr[4];
#pragma unroll
                for (int ks = 0; ks < 4; ++ks) {
                    const int u0 = ks * 8 + ksel * 2;           // 16B-unit index
                    float4 lo = *(const float4*)&xt[(rA * 32 + (u0 ^ sw)) * 4];
                    float4 hi = *(const float4*)&xt[(rA * 32 + ((u0 + 1) ^ sw)) * 4];
                    union { short8 s; unsigned u[4]; } t;
                    t.u[0] = pack2(lo.x, lo.y); t.u[1] = pack2(lo.z, lo.w);
                    t.u[2] = pack2(hi.x, hi.y); t.u[3] = pack2(hi.z, hi.w);
                    afr[ks] = t.s;
                }
#pragma unroll
                for (int ct = 0; ct < 2; ++ct)
#pragma unroll
                    for (int ks = 0; ks < 4; ++ks)
                        acc[rt][ct] = __builtin_amdgcn_mfma_f32_16x16x32_bf16(
                            afr[ks], bfr[ct][ks], acc[rt][ct], 0, 0, 0);
            }
        }
        BARRIER();             // all waves done reading xt

        // ---- next tile DMA in flight across the whole epilogue
        if (it + 1 < ITERS) {
            const float* src = x + xorg + (size_t)(it + 1) * ROWS * IND;
#pragma unroll
            for (int i = 0; i < 8; ++i)
                __builtin_amdgcn_global_load_lds(
                    (const __attribute__((address_space(1))) unsigned*)(src + goff[i]),
                    (__attribute__((address_space(3))) unsigned*)(xt + (i * 256 + tid) * 4),
                    16, 0, 0);
        }

        // ---- bias into acc (x_r = A*W_r + b_r)
#pragma unroll
        for (int rt = 0; rt < 4; ++rt)
#pragma unroll
            for (int rg = 0; rg < 4; ++rg) {
                acc[rt][0][rg] += bi0;
                acc[rt][1][rg] += bi1;
            }

        // ---- out store straight from acc (4x64B segments per instr)
        {
            float* ob = out + ((size_t)b * NROWS + blk * (ITERS * ROWS) + it * ROWS) * HC;
#pragma unroll
            for (int rt = 0; rt < 4; ++rt) {
                float* rp = ob + (size_t)(rt * 16 + (lane >> 4) * 4) * HC;
#pragma unroll
                for (int rg = 0; rg < 4; ++rg) {
                    rp[rg * HC + c0] = acc[rt][0][rg];
                    rp[rg * HC + c1] = acc[rt][1][rg];
                }
            }
        }

        // ---- logits for head wv: per-lane 2-col partial, reduce over lane&15
        float s[4][4];
#pragma unroll
        for (int rt = 0; rt < 4; ++rt)
#pragma unroll
            for (int rg = 0; rg < 4; ++rg) {
                float v0 = q0 + acc[rt][0][rg]; v0 = v0 > 0.f ? v0 : NEG * v0;
                float v1 = q1 + acc[rt][1][rg]; v1 = v1 > 0.f ? v1 : NEG * v1;
                s[rt][rg] = fmaf(v0, a0, v1 * a1);
            }
#pragma unroll
        for (int mk = 1; mk < 16; mk <<= 1)
#pragma unroll
            for (int rt = 0; rt < 4; ++rt)
#pragma unroll
                for (int rg = 0; rg < 4; ++rg)
                    s[rt][rg] += __shfl_xor(s[rt][rg], mk);
        // lane now holds full logits for its 16 rows (replicated over lane&15)

        // ---- online softmax (head-local, all in registers)
        float mx = s[0][0];
#pragma unroll
        for (int rt = 0; rt < 4; ++rt)
#pragma unroll
            for (int rg = 0; rg < 4; ++rg) mx = fmaxf(mx, s[rt][rg]);
        mx = fmaxf(mx, __shfl_xor(mx, 16));
        mx = fmaxf(mx, __shfl_xor(mx, 32));
        const float Mnew = fmaxf(Mrun, mx);
        const float sc   = __expf(Mrun - Mnew);     // 0 on first iter (-inf)
        float sumw = 0.f, p0 = 0.f, p1 = 0.f;
#pragma unroll
        for (int rt = 0; rt < 4; ++rt)
#pragma unroll
            for (int rg = 0; rg < 4; ++rg) {
                const float w = __expf(s[rt][rg] - Mnew);
                sumw += w;
                p0 = fmaf(w, acc[rt][0][rg], p0);
                p1 = fmaf(w, acc[rt][1][rg], p1);
            }
        sumw += __shfl_xor(sumw, 16); sumw += __shfl_xor(sumw, 32);
        p0   += __shfl_xor(p0, 16);   p0   += __shfl_xor(p0, 32);
        p1   += __shfl_xor(p1, 16);   p1   += __shfl_xor(p1, 32);
        Srun = Srun * sc + sumw;
        P0   = P0 * sc + p0;
        P1   = P1 * sc + p1;
        Mrun = Mnew;
    }

    // ---- write block partials (per head wv)
    float* pb = part + (size_t)(b * NBLK + blk) * PART_STRIDE;
    if (lane == 0) { pb[wv] = Mrun; pb[4 + wv] = Srun; }
    if (lane < 16) { pb[8 + c0] = P0; pb[8 + c1] = P1; }
}

// ---------------- kernel C: combine partials, write center row ---------------
__global__ void gat_final(const float* __restrict__ part, float* __restrict__ out)
{
    const int b = blockIdx.x, t = threadIdx.x;   // 128 threads: t = h*32+c
    const int h = t >> 5;
    const float* pb = part + (size_t)b * NBLK * PART_STRIDE;
    float Mg = -INFINITY;
    for (int i = 0; i < NBLK; ++i) Mg = fmaxf(Mg, pb[i * PART_STRIDE + h]);
    float Sg = 0.f, Pg = 0.f;
    for (int i = 0; i < NBLK; ++i) {
        const float sc = __expf(pb[i * PART_STRIDE + h] - Mg);
        Sg += pb[i * PART_STRIDE + 4 + h] * sc;
        Pg  = fmaf(pb[i * PART_STRIDE + 8 + t], sc, Pg);
    }
    out[(size_t)b * NROWS * HC + t] = Pg / Sg;
}

extern "C" void kernel_launch(void* const* d_in, const int* in_sizes, int n_in,
                              void* d_out, int out_size, void* d_ws, size_t ws_size,
                              hipStream_t stream)
{
    const float* x   = (const float*)d_in[0];
    const float* Wl  = (const float*)d_in[1];
    const float* bl  = (const float*)d_in[2];
    const float* Wr  = (const float*)d_in[3];
    const float* br  = (const float*)d_in[4];
    const float* att = (const float*)d_in[5];
    float* out = (float*)d_out;

    float* xl0  = (float*)d_ws;                // 32*128 f32
    float* part = xl0 + BATCH * 128;           // 32*32*136 f32

    gat_center<<<BATCH, 128, 0, stream>>>(x, Wl, bl, xl0);
    gat_main<<<BATCH * NBLK, 256, 0, stream>>>(x, Wr, br, att, xl0, out, part);
    gat_final<<<BATCH, 128, 0, stream>>>(part, out);
}